// Round 6
// baseline (16210.529 us; speedup 1.0000x reference)
//
#include <hip/hip_runtime.h>

// VQ: replicate the harness np-fp32 reference bit-for-bit, then emit idx+1.
// R5 4.0ms was LDS-return-BW bound: wall ~ FMA-floor(1.75ms) x ratio, where
// ratio = 6(M+N)/(M*N) (b128 ~12cyc vs fma 2cyc, 8 waves share 1 LDS pipe).
// R4 4x4: 3.0x -> 7.65ms; R5 8x8: 1.5x -> 4.0ms (ratio 1.9 matched). R6: 8x16
// micro-tile -> ratio 1.125. Tile 128 tok x 256-code chunks, k in 32-float
// segments (stride 9 f4), LDS 57KB -> 2 blocks/CU, grid 512.
// Arithmetic bit-identical to R4/R5: per-(t,c) ascending-k fmaf chain, np
// pairwise A/C, fl(A-2B)+C, first-index ties, idx+1 (absmax must repeat 32.0).

#define NCODES 8192
#define DDIM   256
#define BT     65536
#define TM     128          // tokens per block
#define TN     256          // codes per chunk
#define NSEG   256          // 32 chunks * 8 k-segments (32 floats each)
#define F4S    9            // f4 row stride (8 data + 1 pad)

// numpy pairwise_sum (scalar path) for n=256 over p_i = fl32(x_i*x_i).
__device__ __forceinline__ float np_pairwise256_sq(const float4* __restrict__ row) {
#pragma clang fp contract(off)
  float half[2];
  #pragma unroll
  for (int h = 0; h < 2; h++) {
    float r0,r1,r2,r3,r4,r5,r6,r7;
    float4 q0 = row[h*32 + 0];
    float4 q1 = row[h*32 + 1];
    r0 = q0.x*q0.x; r1 = q0.y*q0.y; r2 = q0.z*q0.z; r3 = q0.w*q0.w;
    r4 = q1.x*q1.x; r5 = q1.y*q1.y; r6 = q1.z*q1.z; r7 = q1.w*q1.w;
    #pragma unroll
    for (int g = 1; g < 16; g++) {
      q0 = row[h*32 + g*2];
      q1 = row[h*32 + g*2 + 1];
      r0 += q0.x*q0.x; r1 += q0.y*q0.y; r2 += q0.z*q0.z; r3 += q0.w*q0.w;
      r4 += q1.x*q1.x; r5 += q1.y*q1.y; r6 += q1.z*q1.z; r7 += q1.w*q1.w;
    }
    half[h] = ((r0+r1) + (r2+r3)) + ((r4+r5) + (r6+r7));
  }
  return half[0] + half[1];
}

__global__ void vq_pre_a(const float* __restrict__ x, float* __restrict__ Astage) {
  const int t = blockIdx.x * 256 + threadIdx.x;
  Astage[t] = np_pairwise256_sq((const float4*)(x + (size_t)t * DDIM));
}

__global__ void vq_pre_c(const float* __restrict__ emb, float* __restrict__ Cws) {
  const int c = blockIdx.x * 256 + threadIdx.x;
  Cws[c] = np_pairwise256_sq((const float4*)(emb + (size_t)c * DDIM));
}

__global__ void vq_init(float* __restrict__ oloss) { *oloss = 0.0f; }

__global__ __launch_bounds__(256, 2)
void vq_main(const float* __restrict__ x, const float* __restrict__ emb,
             const float* __restrict__ Cws, float* __restrict__ y,
             float* __restrict__ oidx, float* __restrict__ oloss) {
  __shared__ float4 xs4[TM * F4S];   // x tile: 128 tokens x 8 f4 (k-segment)
  __shared__ float4 es4[TN * F4S];   // e tile: 256 codes  x 8 f4
  __shared__ float  Cs[TN];          // np-fp32 ||e||^2 per chunk code
  __shared__ int    idx_sh[TM];
  __shared__ float  red[4];

  const int tid = threadIdx.x;
  const int ry = tid >> 4;   // 0..15 -> tokens ry+16m (m=0..7)
  const int rx = tid & 15;   // 0..15 -> codes  rx+16n (n=0..15)
  const int tok0 = blockIdx.x * TM;

  const float4* x4g = (const float4*)x;    // [BT][64]
  const float4* e4g = (const float4*)emb;  // [NCODES][64]

  float A_reg[8];
  #pragma unroll
  for (int m = 0; m < 8; m++) A_reg[m] = oidx[tok0 + ry + 16 * m];  // staged A

  float best[8];
  int   i1[8];
  #pragma unroll
  for (int m = 0; m < 8; m++) { best[m] = 1e30f; i1[m] = 0; }

  float acc[8][16];

  for (int seg = 0; seg < NSEG; ++seg) {
    const int chunk = seg >> 3;
    const int kq = seg & 7;            // k-segment within chunk: floats kq*32..kq*32+31

    __syncthreads();                   // prior readers of LDS done

    // stage x-tile: 1024 f4, 4 per thread (rows g>>3, cols g&7 -> 128B runs)
    {
      float4 tx[4];
      #pragma unroll
      for (int r = 0; r < 4; r++) {
        const int g = tid + 256 * r, row = g >> 3, col = g & 7;
        tx[r] = x4g[(size_t)(tok0 + row) * 64 + kq * 8 + col];
      }
      float4 te[8];
      #pragma unroll
      for (int r = 0; r < 8; r++) {
        const int g = tid + 256 * r, row = g >> 3, col = g & 7;
        te[r] = e4g[(size_t)(chunk * TN + row) * 64 + kq * 8 + col];
      }
      #pragma unroll
      for (int r = 0; r < 4; r++) {
        const int g = tid + 256 * r, row = g >> 3, col = g & 7;
        xs4[row * F4S + col] = tx[r];
      }
      #pragma unroll
      for (int r = 0; r < 8; r++) {
        const int g = tid + 256 * r, row = g >> 3, col = g & 7;
        es4[row * F4S + col] = te[r];
      }
    }
    if (kq == 0 && tid < TN) Cs[tid] = Cws[chunk * TN + tid];
    __syncthreads();                   // tiles + Cs visible

    if (kq == 0) {
      #pragma unroll
      for (int m = 0; m < 8; m++)
        #pragma unroll
        for (int n = 0; n < 16; n++) acc[m][n] = 0.0f;
    }

    // Sequential ascending-k FMA chain per (token,code) — bit-identical chain.
    #pragma unroll
    for (int kk = 0; kk < 8; kk++) {
      float4 b[16];
      #pragma unroll
      for (int n = 0; n < 16; n++) b[n] = es4[(rx + 16 * n) * F4S + kk];
      #pragma unroll
      for (int m = 0; m < 8; m++) {
        const float4 a = xs4[(ry + 16 * m) * F4S + kk];
        #pragma unroll
        for (int n = 0; n < 16; n++) {
          acc[m][n] = fmaf(a.x, b[n].x, acc[m][n]);
          acc[m][n] = fmaf(a.y, b[n].y, acc[m][n]);
          acc[m][n] = fmaf(a.z, b[n].z, acc[m][n]);
          acc[m][n] = fmaf(a.w, b[n].w, acc[m][n]);
        }
      }
    }

    if (kq == 7) {                     // finalize chunk: np-fp32 dist, argmin
      const int c0 = chunk * TN;
      #pragma unroll
      for (int n = 0; n < 16; n++) {   // ascending code order within thread
        const float Cv = Cs[rx + 16 * n];
        const int c = c0 + rx + 16 * n;
        #pragma unroll
        for (int m = 0; m < 8; m++) {
          const float t1 = fmaf(-2.0f, acc[m][n], A_reg[m]); // fl(A-2B)
          const float t2 = t1 + Cv;                           // fl(.+C)
          if (t2 < best[m]) { best[m] = t2; i1[m] = c; }      // strict < => first idx
        }
      }
    }
  }

  // ---- cross-thread argmin reduce (16 partials/token), min-index on ties ----
  __syncthreads();
  float* bv1 = (float*)xs4;          // [128][16]
  int*   bi  = (int*)es4;            // [128][16]
  #pragma unroll
  for (int m = 0; m < 8; m++) {
    bv1[(ry + 16 * m) * 16 + rx] = best[m];
    bi [(ry + 16 * m) * 16 + rx] = i1[m];
  }
  __syncthreads();
  if (tid < TM) {
    float v = bv1[tid * 16];
    int   id = bi[tid * 16];
    for (int t = 1; t < 16; t++) {
      const float vv = bv1[tid * 16 + t];
      const int   ii = bi [tid * 16 + t];
      if (vv < v || (vv == v && ii < id)) { v = vv; id = ii; }
    }
    idx_sh[tid] = id;
    oidx[tok0 + tid] = (float)(id + 1);    // ref idx channel is 1-based
  }
  __syncthreads();

  // ---- gather y = emb[idx] (0-based), accumulate loss ----
  float lsum = 0.0f;
  float4* y4 = (float4*)y;
  #pragma unroll
  for (int r = 0; r < 32; r++) {
    const int g = tid + 256 * r, row = g >> 6, c4 = g & 63;
    const float4 ev = e4g[(size_t)idx_sh[row] * 64 + c4];
    const float4 xv = x4g[(size_t)(tok0 + row) * 64 + c4];
    y4[(size_t)(tok0 + row) * 64 + c4] = ev;
    const float dx = ev.x - xv.x, dy = ev.y - xv.y, dz = ev.z - xv.z, dw = ev.w - xv.w;
    lsum += dx * dx + dy * dy + dz * dz + dw * dw;
  }
  #pragma unroll
  for (int off = 32; off; off >>= 1) lsum += __shfl_down(lsum, off);
  if ((tid & 63) == 0) red[tid >> 6] = lsum;
  __syncthreads();
  if (tid == 0) atomicAdd(oloss, red[0] + red[1] + red[2] + red[3]);
}

__global__ void vq_fin(float* __restrict__ oloss) {
  *oloss = *oloss * (1.0f / 16777216.0f);
}

extern "C" void kernel_launch(void* const* d_in, const int* in_sizes, int n_in,
                              void* d_out, int out_size, void* d_ws, size_t ws_size,
                              hipStream_t stream) {
  const float* x   = (const float*)d_in[0];   // [16,4096,256]
  const float* emb = (const float*)d_in[1];   // [8192,256]

  float* y     = (float*)d_out;                // [16,4096,256]
  float* oidx  = y + (size_t)BT * DDIM;        // [16,4096] idx channel
  float* oloss = oidx + BT;                    // [1]
  float* Cws   = (float*)d_ws;                 // [8192] np-fp32 ||e||^2

  vq_init <<<1, 1,          0, stream>>>(oloss);
  vq_pre_a<<<BT / 256, 256, 0, stream>>>(x, oidx);      // stage A in idx region
  vq_pre_c<<<NCODES/256,256,0, stream>>>(emb, Cws);
  vq_main <<<BT / TM,  256, 0, stream>>>(x, emb, Cws, y, oidx, oloss);
  vq_fin  <<<1, 1,          0, stream>>>(oloss);
}